// Round 3
// baseline (134.293 us; speedup 1.0000x reference)
//
#include <hip/hip_runtime.h>

typedef short s16x8 __attribute__((ext_vector_type(8)));
typedef float fx4 __attribute__((ext_vector_type(4)));

#define NROWS 65536
#define BM 64
#define PSTR 133   // 133 mod 32 = 5 (odd) -> conflict-free row-major f32 access

#define MFMA(a, b, c) __builtin_amdgcn_mfma_f32_16x16x32_bf16((a), (b), (c), 0, 0, 0)

__device__ __forceinline__ unsigned short f2bf(float f) {
  union { float f; unsigned u; } v; v.f = f;
  unsigned r = v.u + 0x7fffu + ((v.u >> 16) & 1u);  // RNE
  return (unsigned short)(r >> 16);
}

// LDS-only barrier: does NOT drain vmcnt -> in-flight global loads (B prefetch)
// and fire-and-forget out[] stores survive. All cross-wave handoffs are LDS.
__device__ __forceinline__ void bar_lds() {
  asm volatile("s_waitcnt lgkmcnt(0)\n\ts_barrier" ::: "memory");
}

// ---------------------------------------------------------------------------
// Pack kernel.
//  blocks 0..1023   : W3P  idx=(((t*8+ks)*4+kc)*128+n)*8+e ; n<64 -> V col t*65+n,
//                     else W col 520+t*64+(n-64); value bf16(W3[k][c]), k=ks*32+kc*8+e
//  blocks 1024..1039: W3X  idx=((ks*4+kc)*16+n)*8+e ; n<8 -> V col n*65+64 else 0
//  blocks 1040..1047: W12 = W1@W2 (f32 acc -> bf16), B-frag order W12P[c*8+k]
//  block  1048      : b12 = b1@W2 + b2 (f32)
// ---------------------------------------------------------------------------
__global__ void pack_weights(const float* __restrict__ W1, const float* __restrict__ b1,
                             const float* __restrict__ W2, const float* __restrict__ b2,
                             const float* __restrict__ W3,
                             unsigned short* __restrict__ W12P, float* __restrict__ b12,
                             unsigned short* __restrict__ W3P, unsigned short* __restrict__ W3X) {
  int blk = blockIdx.x, tid = threadIdx.x;
  if (blk < 1024) {
    int i3 = blk * 256 + tid;
    int e = i3 & 7, n = (i3 >> 3) & 127, kc = (i3 >> 10) & 3, ks = (i3 >> 12) & 7, t = i3 >> 15;
    int k = ks * 32 + kc * 8 + e;
    int c = (n < 64) ? (t * 65 + n) : (520 + t * 64 + (n - 64));
    W3P[i3] = f2bf(W3[k * 1032 + c]);
  } else if (blk < 1040) {
    int ix = (blk - 1024) * 256 + tid;
    int e = ix & 7, n = (ix >> 3) & 15, kc = (ix >> 7) & 3, ks = ix >> 9;
    int k = ks * 32 + kc * 8 + e;
    float v = (n < 8) ? W3[k * 1032 + n * 65 + 64] : 0.0f;
    W3X[ix] = f2bf(v);
  } else if (blk < 1048) {
    int k = blk - 1040, c = tid;
    float s = 0.0f;
    for (int m = 0; m < 256; m++) s += W1[k * 256 + m] * W2[m * 256 + c];
    W12P[c * 8 + k] = f2bf(s);
  } else {
    int c = tid;
    float s = b2[c];
    for (int m = 0; m < 256; m++) s += b1[m] * W2[m * 256 + c];
    b12[c] = s;
  }
}

// ---------------------------------------------------------------------------
// Fused MLP + piecewise-quadratic transform. 256 threads (4 waves), 64 rows/block.
// Layer1+2 collapsed into one K=8 MFMA pass (W12). GEMM3 col-partitioned
// (wave w: cols [32w,32w+32), B direct from L2; A-frags ks0..5 in regs,
// ks6..7 re-read from H2). Single params buffer -> 49408 B LDS -> 3 blocks/CU.
// LDS map:
//   P  [0,34048)      : params f32 [64][133]; h bf16 [64][256] swizzled aliases it
//   XC [34048,35072)  : xc bf16 [64][8]
//   xt [35072,37120)  : [64][8] f32
//   v64[37120,39168)  : [64][8] f32 (raw 65th-V params)
//   lj [39168,41216)  : [64][8] f32
//   H2 [41216,49408)  : h k=192..255 slice, bf16 [64][64] swizzled
// ---------------------------------------------------------------------------
__global__ __launch_bounds__(256, 3) void fused_pwquad(
    const float* __restrict__ x, const float* __restrict__ b3,
    const unsigned short* __restrict__ W12P, const float* __restrict__ b12,
    const unsigned short* __restrict__ W3P, const unsigned short* __restrict__ W3X,
    float* __restrict__ out)
{
  __shared__ char smem[49408];
  char*  H     = smem;
  float* P     = (float*)smem;
  char*  XC    = smem + 34048;
  float* xt_s  = (float*)(smem + 35072);
  float* v64_s = (float*)(smem + 37120);
  float* lj_s  = (float*)(smem + 39168);
  char*  H2    = smem + 41216;

  const int tid  = threadIdx.x;
  const int lane = tid & 63;
  const int w    = tid >> 6;
  const int kc   = lane >> 4;
  const int l15  = lane & 15;
  const int r0   = blockIdx.x * BM;

  // ---- phase 0: load x tile; emit copied (even) z cols; stash xc(bf16)/xt ----
  {
    const float4* xin = (const float4*)(x + (size_t)r0 * 16);
    float4 v = xin[tid];
    int row = tid >> 2, q = tid & 3;
    out[(size_t)(r0 + row) * 16 + 4 * q + 0] = fminf(v.x, 1.0f);
    out[(size_t)(r0 + row) * 16 + 4 * q + 2] = fminf(v.z, 1.0f);
    unsigned pk = (unsigned)f2bf(v.x) | ((unsigned)f2bf(v.z) << 16);
    *(unsigned*)(XC + row * 16 + q * 4) = pk;
    float2 t2; t2.x = v.y; t2.y = v.w;
    *(float2*)(xt_s + row * 8 + 2 * q) = t2;
  }
  bar_lds();

  // ---- GEMM-h: h = relu(xc @ W12 + b12), K=8 (one MFMA k-step) ----
  {
    s16x8 ah[4] = {};
    if (kc == 0) {
      #pragma unroll
      for (int m = 0; m < 4; m++) ah[m] = *(const s16x8*)(XC + (m * 16 + l15) * 16);
    }
    s16x8 bh[4];
    #pragma unroll
    for (int nt = 0; nt < 4; nt++)
      bh[nt] = *(const s16x8*)(W12P + (size_t)(w * 64 + nt * 16 + l15) * 8);
    fx4 acc[4][4];
    #pragma unroll
    for (int m = 0; m < 4; m++)
      #pragma unroll
      for (int nt = 0; nt < 4; nt++) acc[m][nt] = (fx4){0.f, 0.f, 0.f, 0.f};
    #pragma unroll
    for (int m = 0; m < 4; m++)
      #pragma unroll
      for (int nt = 0; nt < 4; nt++) acc[m][nt] = MFMA(ah[m], bh[nt], acc[m][nt]);
    #pragma unroll
    for (int nt = 0; nt < 4; nt++) {
      int col = w * 64 + nt * 16 + l15;
      float bias = b12[col];
      #pragma unroll
      for (int m = 0; m < 4; m++) {
        #pragma unroll
        for (int rg = 0; rg < 4; rg++) {
          int row = m * 16 + kc * 4 + rg;
          float v = fmaxf(acc[m][nt][rg] + bias, 0.0f);
          int byte = (row << 9) + (col << 1);
          byte ^= ((row & 7) << 4);
          *(unsigned short*)(H + byte) = f2bf(v);
        }
      }
    }
  }
  bar_lds();

  // ---- hoist A-frags ks0..5 to regs; copy ks6..7 slice to H2; V65 GEMM ----
  s16x8 a3[4][6];
  #pragma unroll
  for (int m = 0; m < 4; m++) {
    #pragma unroll
    for (int ks = 0; ks < 6; ks++) {
      int row = m * 16 + l15;
      int byte = (row << 9) + ks * 64 + (kc << 4);
      byte ^= ((row & 7) << 4);
      a3[m][ks] = *(const s16x8*)(H + byte);
    }
  }
  #pragma unroll
  for (int i2 = 0; i2 < 2; i2++) {   // H2 copy: 512 16B chunks, 2/thread
    int c = tid * 2 + i2;
    int row = c >> 3, i = c & 7;
    int sw = ((i << 4) ^ ((row & 7) << 4));
    *(s16x8*)(H2 + (row << 7) + sw) = *(const s16x8*)(H + (row << 9) + 384 + sw);
  }
  #pragma unroll
  for (int m = 0; m < 4; m++) {
    if (m == w) {  // wave-uniform: V65 for this wave's rows
      fx4 accx = (fx4){0.f, 0.f, 0.f, 0.f};
      #pragma unroll
      for (int ks = 0; ks < 6; ks++) {
        s16x8 bx = *(const s16x8*)(W3X + ((size_t)(ks * 4 + kc) * 16 + l15) * 8);
        accx = MFMA(a3[m][ks], bx, accx);
      }
      #pragma unroll
      for (int ks = 6; ks < 8; ks++) {
        int row = m * 16 + l15;
        int b2o = (row << 7) + ((((ks - 6) << 6) | (kc << 4)) ^ ((row & 7) << 4));
        s16x8 am = *(const s16x8*)(H2 + b2o);
        s16x8 bx = *(const s16x8*)(W3X + ((size_t)(ks * 4 + kc) * 16 + l15) * 8);
        accx = MFMA(am, bx, accx);
      }
      if (l15 < 8) {
        float bias = b3[l15 * 65 + 64];
        #pragma unroll
        for (int rg = 0; rg < 4; rg++) {
          int row = m * 16 + kc * 4 + rg;
          v64_s[row * 8 + l15] = accx[rg] + bias;
        }
      }
    }
  }
  bar_lds();  // H dead -> P; H2/v64/xt ready

  // B-frag prefetch (t=0, ks=0)
  s16x8 bpre0, bpre1;
  {
    const unsigned short* bp = W3P + ((size_t)kc * 128 + w * 32 + l15) * 8;
    bpre0 = *(const s16x8*)(bp);
    bpre1 = *(const s16x8*)(bp + 128);
  }

  #pragma unroll 1
  for (int t = 0; t < 8; t++) {
    fx4 acc3[4][2];
    #pragma unroll
    for (int m = 0; m < 4; m++) { acc3[m][0] = (fx4){0.f,0.f,0.f,0.f}; acc3[m][1] = (fx4){0.f,0.f,0.f,0.f}; }

    #pragma unroll
    for (int m = 0; m < 4; m++) {
      acc3[m][0] = MFMA(a3[m][0], bpre0, acc3[m][0]);
      acc3[m][1] = MFMA(a3[m][0], bpre1, acc3[m][1]);
    }
    #pragma unroll
    for (int ks = 1; ks < 6; ks++) {
      const unsigned short* bp = W3P + ((size_t)((t * 8 + ks) * 4 + kc) * 128 + w * 32 + l15) * 8;
      s16x8 b0 = *(const s16x8*)(bp);
      s16x8 b1 = *(const s16x8*)(bp + 128);
      #pragma unroll
      for (int m = 0; m < 4; m++) {
        acc3[m][0] = MFMA(a3[m][ks], b0, acc3[m][0]);
        acc3[m][1] = MFMA(a3[m][ks], b1, acc3[m][1]);
      }
    }
    #pragma unroll
    for (int ks = 6; ks < 8; ks++) {
      const unsigned short* bp = W3P + ((size_t)((t * 8 + ks) * 4 + kc) * 128 + w * 32 + l15) * 8;
      s16x8 b0 = *(const s16x8*)(bp);
      s16x8 b1 = *(const s16x8*)(bp + 128);
      #pragma unroll
      for (int m = 0; m < 4; m++) {
        int row = m * 16 + l15;
        int b2o = (row << 7) + ((((ks - 6) << 6) | (kc << 4)) ^ ((row & 7) << 4));
        s16x8 am = *(const s16x8*)(H2 + b2o);
        acc3[m][0] = MFMA(am, b0, acc3[m][0]);
        acc3[m][1] = MFMA(am, b1, acc3[m][1]);
      }
    }

    if (t < 7) {  // prefetch next t's ks0 frags; survive the LDS-only barriers
      const unsigned short* bp = W3P + ((size_t)((t + 1) * 32 + kc) * 128 + w * 32 + l15) * 8;
      bpre0 = *(const s16x8*)(bp);
      bpre1 = *(const s16x8*)(bp + 128);
    }

    bar_lds();  // A: postprocess(t-1) reads of P done

    #pragma unroll
    for (int nt = 0; nt < 2; nt++) {
      int n = w * 32 + nt * 16 + l15;
      bool isV = (n < 64);
      float bias = isV ? b3[t * 65 + n] : b3[520 + t * 64 + (n - 64)];
      int ci = isV ? n : (n + 1);
      #pragma unroll
      for (int m = 0; m < 4; m++) {
        #pragma unroll
        for (int rg = 0; rg < 4; rg++) {
          int row = m * 16 + kc * 4 + rg;
          P[row * PSTR + ci] = acc3[m][nt][rg] + bias;
        }
      }
    }

    bar_lds();  // B: params complete

    // ---------- postprocess channel t: 4 lanes per row, fused single pass ----------
    {
      int row = tid >> 2, sub = tid & 3;
      const float* prow = P + row * PSTR;
      float xtv = xt_s[row * 8 + t];

      // W softmax pass
      float wr[16];
      #pragma unroll
      for (int i = 0; i < 4; i++) {
        float4 v4 = *(const float4*)(prow + 65 + sub * 16 + 4 * i);
        wr[4*i] = v4.x; wr[4*i+1] = v4.y; wr[4*i+2] = v4.z; wr[4*i+3] = v4.w;
      }
      float wmax = wr[0];
      #pragma unroll
      for (int j = 1; j < 16; j++) wmax = fmaxf(wmax, wr[j]);
      wmax = fmaxf(wmax, __shfl_xor(wmax, 1, 64));
      wmax = fmaxf(wmax, __shfl_xor(wmax, 2, 64));

      float wj[16], esum = 0.0f;
      #pragma unroll
      for (int j = 0; j < 16; j++) { wj[j] = __expf(wr[j] - wmax); esum += wj[j]; }

      int gbase = lane & ~3;
      float g0 = __shfl(esum, gbase + 0, 64);
      float g1 = __shfl(esum, gbase + 1, 64);
      float g2 = __shfl(esum, gbase + 2, 64);
      float g3 = __shfl(esum, gbase + 3, 64);
      float invS = 1.0f / ((g0 + g1) + (g2 + g3));
      float ebase = 0.0f;
      if (sub > 0) ebase += g0;
      if (sub > 1) ebase += g1;
      if (sub > 2) ebase += g2;

      // fused stream: ev, dl, prefix(cpart), crossing capture
      float run = ebase * invS;
      float evc = __expf(prow[sub * 16]);
      float evprev = evc, tlast = 0.0f;
      float dl = 0.0f, cpart = 0.0f;
      float wpadc = 0.0f, wbbc = 1.0f, evb = evc, evb1 = evc;
      int cnt = 0;
      #pragma unroll
      for (int j = 0; j < 16; j++) {
        float vr = (sub == 3 && j == 15) ? v64_s[row * 8 + t] : prow[sub * 16 + j + 1];
        float evn = __expf(vr);
        float wbj = wj[j] * invS;
        float nw = run + wbj;
        float term = (evc + evn) * wbj;
        bool le = (nw <= xtv);
        bool hit = (!le) && (run <= xtv);
        dl += term;
        if (le) { cpart += term; cnt++; }
        if (hit) { wpadc = run; wbbc = wbj; evb = evc; evb1 = evn; }
        tlast = term;
        evprev = evc;
        run = nw; evc = evn;
      }
      int bloc = (cnt < 16) ? (sub * 16 + cnt) : 64;
      int bmin = min(bloc, __shfl_xor(bloc, 1, 64));
      bmin = min(bmin, __shfl_xor(bmin, 2, 64));

      float d0 = __shfl(dl, gbase + 0, 64);
      float d1 = __shfl(dl, gbase + 1, 64);
      float d2 = __shfl(dl, gbase + 2, 64);
      float d3 = __shfl(dl, gbase + 3, 64);
      float denom2 = (d0 + d1) + (d2 + d3);
      float cbase2 = 0.0f;
      if (sub > 0) cbase2 += d0;
      if (sub > 1) cbase2 += d1;
      if (sub > 2) cbase2 += d2;

      if (bmin == 64) {  // no strict crossing: continuous fallback b=63 (sub3 owns)
        wbbc = wj[15] * invS;
        wpadc = run - wbbc;
        evb = evprev; evb1 = evc;
        cpart = dl - tlast;
        bmin = 63;
      }

      if (sub == (bmin >> 4)) {
        float alpha = (xtv - wpadc) / wbbc;
        float denom = 0.5f * denom2;
        float Cnum = (alpha * (evb + 0.5f * alpha * (evb1 - evb))) * wbbc
                   + 0.5f * (cbase2 + cpart);
        out[(size_t)(r0 + row) * 16 + 2 * t + 1] = fminf(Cnum / denom, 1.0f);
        float qn = evb + alpha * (evb1 - evb);
        lj_s[row * 8 + t] = __logf(qn) - __logf(denom);
      }
    }
  }

  // ---- log_J = sum_t log(q_t): wave w emits its own 16 rows (intra-wave lj) ----
  if (lane < 16) {
    int row = w * 16 + lane;
    float s = 0.0f;
    #pragma unroll
    for (int t = 0; t < 8; t++) s += lj_s[row * 8 + t];
    out[(size_t)NROWS * 16 + r0 + row] = s;
  }
}

extern "C" void kernel_launch(void* const* d_in, const int* in_sizes, int n_in,
                              void* d_out, int out_size, void* d_ws, size_t ws_size,
                              hipStream_t stream) {
  const float* x  = (const float*)d_in[0];
  const float* W1 = (const float*)d_in[1];
  const float* b1 = (const float*)d_in[2];
  const float* W2 = (const float*)d_in[3];
  const float* b2 = (const float*)d_in[4];
  const float* W3 = (const float*)d_in[5];
  const float* b3 = (const float*)d_in[6];

  unsigned short* W12P = (unsigned short*)d_ws;                      // 4096 B
  float*          b12  = (float*)((char*)d_ws + 4096);               // 1024 B
  unsigned short* W3P  = (unsigned short*)((char*)d_ws + 5120);      // 524288 B
  unsigned short* W3X  = (unsigned short*)((char*)d_ws + 529408);    // 8192 B

  pack_weights<<<dim3(1049), dim3(256), 0, stream>>>(W1, b1, W2, b2, W3, W12P, b12, W3P, W3X);
  fused_pwquad<<<dim3(NROWS / BM), dim3(256), 0, stream>>>(
      x, b3, W12P, b12, W3P, W3X, (float*)d_out);
}

// Round 4
// 85.617 us; speedup vs baseline: 1.5685x; 1.5685x over previous
//
#include <hip/hip_runtime.h>

typedef short s16x8 __attribute__((ext_vector_type(8)));
typedef float fx4 __attribute__((ext_vector_type(4)));

#define NROWS 65536
#define BM 64
#define PSTR 133   // 133 mod 32 = 5 (odd) -> conflict-free row-major f32 access

#define MFMA(a, b, c) __builtin_amdgcn_mfma_f32_16x16x32_bf16((a), (b), (c), 0, 0, 0)

__device__ __forceinline__ unsigned short f2bf(float f) {
  union { float f; unsigned u; } v; v.f = f;
  unsigned r = v.u + 0x7fffu + ((v.u >> 16) & 1u);  // RNE
  return (unsigned short)(r >> 16);
}

// LDS-only barrier: does NOT drain vmcnt -> in-flight global loads (B prefetch)
// and fire-and-forget out[] stores survive. All cross-wave handoffs are LDS.
__device__ __forceinline__ void bar_lds() {
  asm volatile("s_waitcnt lgkmcnt(0)\n\ts_barrier" ::: "memory");
}

// ---------------------------------------------------------------------------
// Pack kernel.
//  blocks 0..1023   : W3P  idx=(((t*8+ks)*4+kc)*128+n)*8+e ; n<64 -> V col t*65+n,
//                     else W col 520+t*64+(n-64); value bf16(W3[k][c]), k=ks*32+kc*8+e
//  blocks 1024..1039: W3X  idx=((ks*4+kc)*16+n)*8+e ; n<8 -> V col n*65+64 else 0
//  blocks 1040..1047: W12 = W1@W2 (f32 acc -> bf16), B-frag order W12P[c*8+k]
//  block  1048      : b12 = b1@W2 + b2 (f32)
// ---------------------------------------------------------------------------
__global__ void pack_weights(const float* __restrict__ W1, const float* __restrict__ b1,
                             const float* __restrict__ W2, const float* __restrict__ b2,
                             const float* __restrict__ W3,
                             unsigned short* __restrict__ W12P, float* __restrict__ b12,
                             unsigned short* __restrict__ W3P, unsigned short* __restrict__ W3X) {
  int blk = blockIdx.x, tid = threadIdx.x;
  if (blk < 1024) {
    int i3 = blk * 256 + tid;
    int e = i3 & 7, n = (i3 >> 3) & 127, kc = (i3 >> 10) & 3, ks = (i3 >> 12) & 7, t = i3 >> 15;
    int k = ks * 32 + kc * 8 + e;
    int c = (n < 64) ? (t * 65 + n) : (520 + t * 64 + (n - 64));
    W3P[i3] = f2bf(W3[k * 1032 + c]);
  } else if (blk < 1040) {
    int ix = (blk - 1024) * 256 + tid;
    int e = ix & 7, n = (ix >> 3) & 15, kc = (ix >> 7) & 3, ks = ix >> 9;
    int k = ks * 32 + kc * 8 + e;
    float v = (n < 8) ? W3[k * 1032 + n * 65 + 64] : 0.0f;
    W3X[ix] = f2bf(v);
  } else if (blk < 1048) {
    int k = blk - 1040, c = tid;
    float s = 0.0f;
    for (int m = 0; m < 256; m++) s += W1[k * 256 + m] * W2[m * 256 + c];
    W12P[c * 8 + k] = f2bf(s);
  } else {
    int c = tid;
    float s = b2[c];
    for (int m = 0; m < 256; m++) s += b1[m] * W2[m * 256 + c];
    b12[c] = s;
  }
}

// ---------------------------------------------------------------------------
// Fused MLP + piecewise-quadratic transform. 256 threads (4 waves), 64 rows/block.
// Layer1+2 collapsed into one K=8 MFMA pass (W12 = W1@W2, f32-accumulated).
// GEMM3 col-partitioned (wave w: cols [32w,32w+32), all 64 rows, B direct from
// L2-resident W3P; A-frags a3[4][8] fully in registers). Double-buffered params
// -> ONE LDS-only barrier per t. launch_bounds(256,2): 256-VGPR budget, NO spill
// (R3's (256,3) spilled to scratch: WRITE_SIZE 7->55MB).
// LDS map (75264 B -> 2 blocks/CU):
//   P0 [0,34048)      : params f32 [64][133]; h bf16 [64][256] swizzled aliases it
//   P1 [34048,68096)  : params buf1
//   XC [68096,69120)  : xc bf16 [64][8]
//   xt [69120,71168)  : [64][8] f32
//   v64[71168,73216)  : [64][8] f32 (raw 65th-V params)
//   lj [73216,75264)  : [64][8] f32
// ---------------------------------------------------------------------------
__global__ __launch_bounds__(256, 2) void fused_pwquad(
    const float* __restrict__ x, const float* __restrict__ b3,
    const unsigned short* __restrict__ W12P, const float* __restrict__ b12,
    const unsigned short* __restrict__ W3P, const unsigned short* __restrict__ W3X,
    float* __restrict__ out)
{
  __shared__ char smem[75264];
  char*  H     = smem;
  float* P0    = (float*)smem;
  float* P1    = (float*)(smem + 34048);
  char*  XC    = smem + 68096;
  float* xt_s  = (float*)(smem + 69120);
  float* v64_s = (float*)(smem + 71168);
  float* lj_s  = (float*)(smem + 73216);

  const int tid  = threadIdx.x;
  const int lane = tid & 63;
  const int w    = tid >> 6;
  const int kc   = lane >> 4;
  const int l15  = lane & 15;
  const int r0   = blockIdx.x * BM;

  // ---- phase 0: load x tile; emit copied (even) z cols; stash xc(bf16)/xt ----
  {
    const float4* xin = (const float4*)(x + (size_t)r0 * 16);
    float4 v = xin[tid];
    int row = tid >> 2, q = tid & 3;
    out[(size_t)(r0 + row) * 16 + 4 * q + 0] = fminf(v.x, 1.0f);
    out[(size_t)(r0 + row) * 16 + 4 * q + 2] = fminf(v.z, 1.0f);
    unsigned pk = (unsigned)f2bf(v.x) | ((unsigned)f2bf(v.z) << 16);
    *(unsigned*)(XC + row * 16 + q * 4) = pk;
    float2 t2; t2.x = v.y; t2.y = v.w;
    *(float2*)(xt_s + row * 8 + 2 * q) = t2;
  }
  bar_lds();

  // ---- GEMM-h: h = relu(xc @ W12 + b12), K=8 (one MFMA k-step) ----
  {
    s16x8 ah[4] = {};
    if (kc == 0) {
      #pragma unroll
      for (int m = 0; m < 4; m++) ah[m] = *(const s16x8*)(XC + (m * 16 + l15) * 16);
    }
    s16x8 bh[4];
    #pragma unroll
    for (int nt = 0; nt < 4; nt++)
      bh[nt] = *(const s16x8*)(W12P + (size_t)(w * 64 + nt * 16 + l15) * 8);
    fx4 acc[4][4];
    #pragma unroll
    for (int m = 0; m < 4; m++)
      #pragma unroll
      for (int nt = 0; nt < 4; nt++) acc[m][nt] = (fx4){0.f, 0.f, 0.f, 0.f};
    #pragma unroll
    for (int m = 0; m < 4; m++)
      #pragma unroll
      for (int nt = 0; nt < 4; nt++) acc[m][nt] = MFMA(ah[m], bh[nt], acc[m][nt]);
    #pragma unroll
    for (int nt = 0; nt < 4; nt++) {
      int col = w * 64 + nt * 16 + l15;
      float bias = b12[col];
      #pragma unroll
      for (int m = 0; m < 4; m++) {
        #pragma unroll
        for (int rg = 0; rg < 4; rg++) {
          int row = m * 16 + kc * 4 + rg;
          float v = fmaxf(acc[m][nt][rg] + bias, 0.0f);
          int byte = (row << 9) + (col << 1);
          byte ^= ((row & 7) << 4);
          *(unsigned short*)(H + byte) = f2bf(v);
        }
      }
    }
  }
  bar_lds();

  // ---- hoist A-frags (all 64 rows, all K) to regs; V65 GEMM ----
  s16x8 a3[4][8];
  #pragma unroll
  for (int m = 0; m < 4; m++) {
    #pragma unroll
    for (int ks = 0; ks < 8; ks++) {
      int row = m * 16 + l15;
      int byte = (row << 9) + ks * 64 + (kc << 4);
      byte ^= ((row & 7) << 4);
      a3[m][ks] = *(const s16x8*)(H + byte);
    }
  }
  #pragma unroll
  for (int m = 0; m < 4; m++) {
    if (m == w) {  // wave-uniform: V65 for this wave's rows (static indexing)
      fx4 accx = (fx4){0.f, 0.f, 0.f, 0.f};
      #pragma unroll
      for (int ks = 0; ks < 8; ks++) {
        s16x8 bx = *(const s16x8*)(W3X + ((size_t)(ks * 4 + kc) * 16 + l15) * 8);
        accx = MFMA(a3[m][ks], bx, accx);
      }
      if (l15 < 8) {
        float bias = b3[l15 * 65 + 64];
        #pragma unroll
        for (int rg = 0; rg < 4; rg++) {
          int row = m * 16 + kc * 4 + rg;
          v64_s[row * 8 + l15] = accx[rg] + bias;
        }
      }
    }
  }
  bar_lds();  // H dead -> params bufs usable; v64/xt visible

  // B-frag prefetch (t=0, ks=0)
  s16x8 bpre0, bpre1;
  {
    const unsigned short* bp = W3P + ((size_t)kc * 128 + w * 32 + l15) * 8;
    bpre0 = *(const s16x8*)(bp);
    bpre1 = *(const s16x8*)(bp + 128);
  }

  #pragma unroll 1
  for (int t = 0; t < 8; t++) {
    float* params = (t & 1) ? P1 : P0;

    fx4 acc3[4][2];
    #pragma unroll
    for (int m = 0; m < 4; m++) { acc3[m][0] = (fx4){0.f,0.f,0.f,0.f}; acc3[m][1] = (fx4){0.f,0.f,0.f,0.f}; }

    #pragma unroll
    for (int m = 0; m < 4; m++) {
      acc3[m][0] = MFMA(a3[m][0], bpre0, acc3[m][0]);
      acc3[m][1] = MFMA(a3[m][0], bpre1, acc3[m][1]);
    }
    #pragma unroll
    for (int ks = 1; ks < 8; ks++) {
      const unsigned short* bp = W3P + ((size_t)((t * 8 + ks) * 4 + kc) * 128 + w * 32 + l15) * 8;
      s16x8 b0 = *(const s16x8*)(bp);
      s16x8 b1 = *(const s16x8*)(bp + 128);
      #pragma unroll
      for (int m = 0; m < 4; m++) {
        acc3[m][0] = MFMA(a3[m][ks], b0, acc3[m][0]);
        acc3[m][1] = MFMA(a3[m][ks], b1, acc3[m][1]);
      }
    }

    // epilogue: wave w writes cols [32w,32w+32) for all 64 rows (other buffer
    // than the one postprocess(t-1) is reading -> no barrier needed before)
    #pragma unroll
    for (int nt = 0; nt < 2; nt++) {
      int n = w * 32 + nt * 16 + l15;
      bool isV = (n < 64);
      float bias = isV ? b3[t * 65 + n] : b3[520 + t * 64 + (n - 64)];
      int ci = isV ? n : (n + 1);
      #pragma unroll
      for (int m = 0; m < 4; m++) {
        #pragma unroll
        for (int rg = 0; rg < 4; rg++) {
          int row = m * 16 + kc * 4 + rg;
          params[row * PSTR + ci] = acc3[m][nt][rg] + bias;
        }
      }
    }

    if (t < 7) {  // prefetch next t's ks0 frags; survive the LDS-only barrier
      const unsigned short* bp = W3P + ((size_t)((t + 1) * 32 + kc) * 128 + w * 32 + l15) * 8;
      bpre0 = *(const s16x8*)(bp);
      bpre1 = *(const s16x8*)(bp + 128);
    }

    bar_lds();  // params[t&1] complete

    // ---------- postprocess channel t: 4 lanes per row, fused single pass ----------
    {
      int row = tid >> 2, sub = tid & 3;   // rows [16w,16w+16) within this wave
      const float* prow = params + row * PSTR;
      float xtv = xt_s[row * 8 + t];

      // W softmax pass
      float wr[16];
      #pragma unroll
      for (int i = 0; i < 4; i++) {
        float4 v4 = *(const float4*)(prow + 65 + sub * 16 + 4 * i);
        wr[4*i] = v4.x; wr[4*i+1] = v4.y; wr[4*i+2] = v4.z; wr[4*i+3] = v4.w;
      }
      float wmax = wr[0];
      #pragma unroll
      for (int j = 1; j < 16; j++) wmax = fmaxf(wmax, wr[j]);
      wmax = fmaxf(wmax, __shfl_xor(wmax, 1, 64));
      wmax = fmaxf(wmax, __shfl_xor(wmax, 2, 64));

      float wj[16], esum = 0.0f;
      #pragma unroll
      for (int j = 0; j < 16; j++) { wj[j] = __expf(wr[j] - wmax); esum += wj[j]; }

      int gbase = lane & ~3;
      float g0 = __shfl(esum, gbase + 0, 64);
      float g1 = __shfl(esum, gbase + 1, 64);
      float g2 = __shfl(esum, gbase + 2, 64);
      float g3 = __shfl(esum, gbase + 3, 64);
      float invS = 1.0f / ((g0 + g1) + (g2 + g3));
      float ebase = 0.0f;
      if (sub > 0) ebase += g0;
      if (sub > 1) ebase += g1;
      if (sub > 2) ebase += g2;

      // fused stream: ev, dl, prefix(cpart), crossing capture
      float run = ebase * invS;
      float evc = __expf(prow[sub * 16]);
      float evprev = evc, tlast = 0.0f;
      float dl = 0.0f, cpart = 0.0f;
      float wpadc = 0.0f, wbbc = 1.0f, evb = evc, evb1 = evc;
      int cnt = 0;
      #pragma unroll
      for (int j = 0; j < 16; j++) {
        float vr = (sub == 3 && j == 15) ? v64_s[row * 8 + t] : prow[sub * 16 + j + 1];
        float evn = __expf(vr);
        float wbj = wj[j] * invS;
        float nw = run + wbj;
        float term = (evc + evn) * wbj;
        bool le = (nw <= xtv);
        bool hit = (!le) && (run <= xtv);
        dl += term;
        if (le) { cpart += term; cnt++; }
        if (hit) { wpadc = run; wbbc = wbj; evb = evc; evb1 = evn; }
        tlast = term;
        evprev = evc;
        run = nw; evc = evn;
      }
      int bloc = (cnt < 16) ? (sub * 16 + cnt) : 64;
      int bmin = min(bloc, __shfl_xor(bloc, 1, 64));
      bmin = min(bmin, __shfl_xor(bmin, 2, 64));

      float d0 = __shfl(dl, gbase + 0, 64);
      float d1 = __shfl(dl, gbase + 1, 64);
      float d2 = __shfl(dl, gbase + 2, 64);
      float d3 = __shfl(dl, gbase + 3, 64);
      float denom2 = (d0 + d1) + (d2 + d3);
      float cbase2 = 0.0f;
      if (sub > 0) cbase2 += d0;
      if (sub > 1) cbase2 += d1;
      if (sub > 2) cbase2 += d2;

      if (bmin == 64) {  // no strict crossing: continuous fallback b=63 (sub3 owns)
        wbbc = wj[15] * invS;
        wpadc = run - wbbc;
        evb = evprev; evb1 = evc;
        cpart = dl - tlast;
        bmin = 63;
      }

      if (sub == (bmin >> 4)) {
        float alpha = (xtv - wpadc) / wbbc;
        float denom = 0.5f * denom2;
        float Cnum = (alpha * (evb + 0.5f * alpha * (evb1 - evb))) * wbbc
                   + 0.5f * (cbase2 + cpart);
        out[(size_t)(r0 + row) * 16 + 2 * t + 1] = fminf(Cnum / denom, 1.0f);
        float qn = evb + alpha * (evb1 - evb);
        lj_s[row * 8 + t] = __logf(qn) - __logf(denom);
      }
    }
    // no trailing barrier: epilogue(t+1) writes the other buffer; the WAR on
    // params[t&1] from epilogue(t+2) is ordered by barrier(t+1)
  }

  // ---- log_J = sum_t log(q_t): wave w emits its own 16 rows (intra-wave lj) ----
  if (lane < 16) {
    int row = w * 16 + lane;
    float s = 0.0f;
    #pragma unroll
    for (int t = 0; t < 8; t++) s += lj_s[row * 8 + t];
    out[(size_t)NROWS * 16 + r0 + row] = s;
  }
}

extern "C" void kernel_launch(void* const* d_in, const int* in_sizes, int n_in,
                              void* d_out, int out_size, void* d_ws, size_t ws_size,
                              hipStream_t stream) {
  const float* x  = (const float*)d_in[0];
  const float* W1 = (const float*)d_in[1];
  const float* b1 = (const float*)d_in[2];
  const float* W2 = (const float*)d_in[3];
  const float* b2 = (const float*)d_in[4];
  const float* W3 = (const float*)d_in[5];
  const float* b3 = (const float*)d_in[6];

  unsigned short* W12P = (unsigned short*)d_ws;                      // 4096 B
  float*          b12  = (float*)((char*)d_ws + 4096);               // 1024 B
  unsigned short* W3P  = (unsigned short*)((char*)d_ws + 5120);      // 524288 B
  unsigned short* W3X  = (unsigned short*)((char*)d_ws + 529408);    // 8192 B

  pack_weights<<<dim3(1049), dim3(256), 0, stream>>>(W1, b1, W2, b2, W3, W12P, b12, W3P, W3X);
  fused_pwquad<<<dim3(NROWS / BM), dim3(256), 0, stream>>>(
      x, b3, W12P, b12, W3P, W3X, (float*)d_out);
}